// Round 8
// baseline (132.260 us; speedup 1.0000x reference)
//
#include <hip/hip_runtime.h>

// GraphSAGE fused layer: out[B,128] = relu(concat(feat[nodes], mean_s feat[neigh])[B,256] @ W[256,128])
// B=50000, S=10, D=128, H=128. fp32 in/out; bf16 MFMA.
//
// R12 (resubmit; prior round died to container infra failure, no counters):
// forced-MLP experiment (R11's intent, executed properly). R11 left
// VGPR_Count=32 -- hipcc's pressure-aware scheduler re-serialized the 22
// named loads; source order alone doesn't survive. Fix per learn_hip: pin
// with __builtin_amdgcn_sched_barrier(0) fences so all 22 load results are
// live across the fence -> distinct VGPRs, single deep VMEM cluster.
// Structure per thread: [11 index loads] |fence| [addr VALU] [22 gathers]
// |fence| [tree reduce]. 32-bit row offsets (feat = 51.2MB < 2^31 B).
// Geometry/phase-2 = proven R6. Facts so far: time invariant to segments
// (R7), occupancy 44-70% (R8/R9), L2-hit bytes (R9); bytes+lines halved
// gave only -14% (R10). This is the last untested lever.

typedef __attribute__((ext_vector_type(8))) short bf16x8;   // 8 bf16 (4 VGPRs)
typedef __attribute__((ext_vector_type(4))) float f32x4;    // MFMA C/D frag

__device__ __forceinline__ unsigned short f2bf(float x) {
  unsigned int u = __float_as_uint(x);
  u += 0x7fffu + ((u >> 16) & 1u);
  return (unsigned short)(u >> 16);
}
__device__ __forceinline__ float4 f4add(float4 a, float4 b) {
  float4 r; r.x = a.x + b.x; r.y = a.y + b.y; r.z = a.z + b.z; r.w = a.w + b.w;
  return r;
}

// W [K=256][H=128] fp32 row-major -> Wt [H=128][K=256] bf16 (LDS transpose).
__global__ void sage_prep_wt2(const float* __restrict__ W,
                              unsigned short* __restrict__ Wt) {
  __shared__ float tile[32][132];                 // +4 pad: no read conflicts
  const int t = threadIdx.x;
  const int kbase = blockIdx.x * 32;
  const float4* w4 = (const float4*)(W + (size_t)kbase * 128);
#pragma unroll
  for (int j = 0; j < 4; ++j) {
    int f4i = t + j * 256;                        // 0..1023, coalesced
    float4 v = w4[f4i];
    int flat = f4i << 2;
    int kk = flat >> 7;                           // 0..31
    int h  = flat & 127;
    tile[kk][h] = v.x; tile[kk][h + 1] = v.y;
    tile[kk][h + 2] = v.z; tile[kk][h + 3] = v.w;
  }
  __syncthreads();
  const int h  = t >> 1;                          // 0..127
  const int kc = (t & 1) * 16;                    // 0 or 16
  unsigned short* dst = &Wt[(size_t)h * 256 + kbase + kc];
#pragma unroll
  for (int j = 0; j < 4; ++j) {
    ushort4 o;
    o.x = f2bf(tile[kc + 4 * j + 0][h]);
    o.y = f2bf(tile[kc + 4 * j + 1][h]);
    o.z = f2bf(tile[kc + 4 * j + 2][h]);
    o.w = f2bf(tile[kc + 4 * j + 3][h]);
    *(ushort4*)&dst[4 * j] = o;
  }
}

__global__ __launch_bounds__(512, 4)
void sage_fused9(const int* __restrict__ nodes,
                 const int* __restrict__ neigh,
                 const float* __restrict__ feat,
                 const unsigned short* __restrict__ Wt,
                 float* __restrict__ out, int B)
{
  constexpr int K = 256, H = 128;
  constexpr int TILE = 32;
  constexpr int STR = K + 8;                   // 264 elems = 528 B rows
  __shared__ unsigned short Clds[TILE * STR];  // 16.9 KB

  const int t = threadIdx.x;
  const int block0 = blockIdx.x * TILE;

  // ---- Phase 1: gather self + mean(neigh) -> LDS tile (bf16) ----
  {
    const int r   = t >> 4;     // 0..31
    const int sub = t & 15;     // float4 index within half-row
    const int b   = block0 + r;
    unsigned short* crow = &Clds[r * STR];
    if (b < B) {
      const float4* f4 = (const float4*)feat;   // feature row = 32 float4
      const int* nb = &neigh[b * 10];
      // --- index loads: 11 independent, issue as one cluster ---
      const int i0 = nb[0], i1 = nb[1], i2 = nb[2], i3 = nb[3], i4 = nb[4];
      const int i5 = nb[5], i6 = nb[6], i7 = nb[7], i8 = nb[8], i9 = nb[9];
      const int is = nodes[b];
      __builtin_amdgcn_sched_barrier(0);
      // --- 32-bit row offsets (feat byte extent 205MB < 2^31) ---
      const int srow = is * 32 + sub;
      const int r0 = i0 * 32 + sub, r1 = i1 * 32 + sub;
      const int r2 = i2 * 32 + sub, r3 = i3 * 32 + sub;
      const int r4 = i4 * 32 + sub, r5 = i5 * 32 + sub;
      const int r6 = i6 * 32 + sub, r7 = i7 * 32 + sub;
      const int r8 = i8 * 32 + sub, r9 = i9 * 32 + sub;

      // --- 22 independent gathers; fence AFTER keeps all issued & live ---
      float4 a0 = f4[r0],      a1 = f4[r1],      a2 = f4[r2],      a3 = f4[r3];
      float4 a4 = f4[r4],      a5 = f4[r5],      a6 = f4[r6],      a7 = f4[r7];
      float4 a8 = f4[r8],      a9 = f4[r9];
      float4 b0 = f4[r0 + 16], b1 = f4[r1 + 16], b2 = f4[r2 + 16], b3 = f4[r3 + 16];
      float4 b4 = f4[r4 + 16], b5 = f4[r5 + 16], b6 = f4[r6 + 16], b7 = f4[r7 + 16];
      float4 b8 = f4[r8 + 16], b9 = f4[r9 + 16];
      float4 s0 = f4[srow],    s1 = f4[srow + 16];
      __builtin_amdgcn_sched_barrier(0);

      // --- balanced trees, consume in issue order ---
      float4 e0 = f4add(a0, a1), e1 = f4add(a2, a3);
      float4 e2 = f4add(a4, a5), e3 = f4add(a6, a7);
      float4 sumA = f4add(f4add(f4add(e0, e1), f4add(e2, e3)), f4add(a8, a9));
      float4 g0 = f4add(b0, b1), g1 = f4add(b2, b3);
      float4 g2 = f4add(b4, b5), g3 = f4add(b6, b7);
      float4 sumB = f4add(f4add(f4add(g0, g1), f4add(g2, g3)), f4add(b8, b9));

      ushort4 o;
      o.x = f2bf(s0.x); o.y = f2bf(s0.y); o.z = f2bf(s0.z); o.w = f2bf(s0.w);
      *(ushort4*)&crow[4 * sub] = o;                       // self K[0..63]
      o.x = f2bf(s1.x); o.y = f2bf(s1.y); o.z = f2bf(s1.z); o.w = f2bf(s1.w);
      *(ushort4*)&crow[64 + 4 * sub] = o;                  // self K[64..127]
      o.x = f2bf(sumA.x * 0.1f); o.y = f2bf(sumA.y * 0.1f);
      o.z = f2bf(sumA.z * 0.1f); o.w = f2bf(sumA.w * 0.1f);
      *(ushort4*)&crow[128 + 4 * sub] = o;                 // mean K[128..191]
      o.x = f2bf(sumB.x * 0.1f); o.y = f2bf(sumB.y * 0.1f);
      o.z = f2bf(sumB.z * 0.1f); o.w = f2bf(sumB.w * 0.1f);
      *(ushort4*)&crow[192 + 4 * sub] = o;                 // mean K[192..255]
    } else {
      ushort4 z; z.x = z.y = z.z = z.w = 0;
      *(ushort4*)&crow[4 * sub] = z;
      *(ushort4*)&crow[64 + 4 * sub] = z;
      *(ushort4*)&crow[128 + 4 * sub] = z;
      *(ushort4*)&crow[192 + 4 * sub] = z;
    }
  }
  __syncthreads();
  __builtin_amdgcn_sched_barrier(0);   // keep Wt loads out of phase-1 lifetime

  // ---- Phase 2: 8 waves x (32 rows x 16 cols) MFMA (proven R6 structure) ----
  const int lane = t & 63;
  const int wave = t >> 6;
  const int m    = lane & 15;
  const int quad = lane >> 4;
  const int cbase = wave * 16;      // 8 waves x 16 = 128 cols

  bf16x8 bfrag[8];
#pragma unroll
  for (int ks = 0; ks < 8; ++ks)
    bfrag[ks] = *(const bf16x8*)&Wt[(cbase + m) * K + ks * 32 + quad * 8];

  f32x4 acc0 = {0.f, 0.f, 0.f, 0.f};
  f32x4 acc1 = {0.f, 0.f, 0.f, 0.f};
#pragma unroll
  for (int ks = 0; ks < 8; ++ks) {
    const int koff = ks * 32 + quad * 8;
    bf16x8 a0 = *(const bf16x8*)&Clds[(m     ) * STR + koff];
    bf16x8 a1 = *(const bf16x8*)&Clds[(16 + m) * STR + koff];
    acc0 = __builtin_amdgcn_mfma_f32_16x16x32_bf16(a0, bfrag[ks], acc0, 0, 0, 0);
    acc1 = __builtin_amdgcn_mfma_f32_16x16x32_bf16(a1, bfrag[ks], acc1, 0, 0, 0);
  }

  // C/D layout: col = lane&15, row = quad*4 + reg (verified m89/m91)
#pragma unroll
  for (int reg = 0; reg < 4; ++reg) {
    const int row0 = quad * 4 + reg;
    const int gb0 = block0 + row0;
    const int gb1 = gb0 + 16;
    if (gb0 < B) out[(size_t)gb0 * H + cbase + m] = fmaxf(acc0[reg], 0.0f);
    if (gb1 < B) out[(size_t)gb1 * H + cbase + m] = fmaxf(acc1[reg], 0.0f);
  }
}

extern "C" void kernel_launch(void* const* d_in, const int* in_sizes, int n_in,
                              void* d_out, int out_size, void* d_ws, size_t ws_size,
                              hipStream_t stream) {
  const int*   nodes = (const int*)d_in[0];
  const int*   neigh = (const int*)d_in[1];
  const float* feat  = (const float*)d_in[2];
  const float* W     = (const float*)d_in[3];
  float*       out   = (float*)d_out;
  const int B = in_sizes[0];                       // 50000

  unsigned short* Wt = (unsigned short*)d_ws;      // 64 KB
  sage_prep_wt2<<<8, 256, 0, stream>>>(W, Wt);
  const int grid = (B + 31) / 32;                  // 1563
  sage_fused9<<<grid, 512, 0, stream>>>(nodes, neigh, feat, Wt, out, B);
}

// Round 9
// 129.249 us; speedup vs baseline: 1.0233x; 1.0233x over previous
//
#include <hip/hip_runtime.h>

// GraphSAGE fused layer: out[B,128] = relu(concat(feat[nodes], mean_s feat[neigh])[B,256] @ W[256,128])
// B=50000, S=10, D=128, H=128. fp32 in/out; bf16 MFMA.
//
// R13: FINAL — revert to best-measured structure (R6: fused 47.4us, total
// 130.1us), keeping R9's LDS-transpose prep_wt2. Gather is at a measured
// hardware service floor: ~13.3 cyc/CU per 128B line, invariant to segment
// geometry (R7), occupancy 44-70% (R8/R9), L2-hit bytes (R9), per-wave
// issue depth (R11/R12). bf16 table (R10) gave -14% fused but +13us prep
// = net worse (workspace re-poison forbids persistence). ~82us of total is
// harness poison-fill overhead (2x268MB @6.4TB/s), outside kernel control.

typedef __attribute__((ext_vector_type(8))) short bf16x8;   // 8 bf16 (4 VGPRs)
typedef __attribute__((ext_vector_type(4))) float f32x4;    // MFMA C/D frag

__device__ __forceinline__ unsigned short f2bf(float x) {
  unsigned int u = __float_as_uint(x);
  u += 0x7fffu + ((u >> 16) & 1u);
  return (unsigned short)(u >> 16);
}

// W [K=256][H=128] fp32 row-major -> Wt [H=128][K=256] bf16 (LDS transpose).
__global__ void sage_prep_wt2(const float* __restrict__ W,
                              unsigned short* __restrict__ Wt) {
  __shared__ float tile[32][132];                 // +4 pad: no read conflicts
  const int t = threadIdx.x;
  const int kbase = blockIdx.x * 32;
  const float4* w4 = (const float4*)(W + (size_t)kbase * 128);
#pragma unroll
  for (int j = 0; j < 4; ++j) {
    int f4i = t + j * 256;                        // 0..1023, coalesced
    float4 v = w4[f4i];
    int flat = f4i << 2;
    int kk = flat >> 7;                           // 0..31
    int h  = flat & 127;
    tile[kk][h] = v.x; tile[kk][h + 1] = v.y;
    tile[kk][h + 2] = v.z; tile[kk][h + 3] = v.w;
  }
  __syncthreads();
  const int h  = t >> 1;                          // 0..127
  const int kc = (t & 1) * 16;                    // 0 or 16
  unsigned short* dst = &Wt[(size_t)h * 256 + kbase + kc];
#pragma unroll
  for (int j = 0; j < 4; ++j) {
    ushort4 o;
    o.x = f2bf(tile[kc + 4 * j + 0][h]);
    o.y = f2bf(tile[kc + 4 * j + 1][h]);
    o.z = f2bf(tile[kc + 4 * j + 2][h]);
    o.w = f2bf(tile[kc + 4 * j + 3][h]);
    *(ushort4*)&dst[4 * j] = o;
  }
}

__global__ __launch_bounds__(512, 6)
void sage_fused3(const int* __restrict__ nodes,
                 const int* __restrict__ neigh,
                 const float* __restrict__ feat,
                 const unsigned short* __restrict__ Wt,
                 float* __restrict__ out, int B)
{
  constexpr int K = 256, H = 128, S = 10;
  constexpr int TILE = 32;
  constexpr int STR = K + 8;                   // 264 elems = 528 B rows
  __shared__ unsigned short Clds[TILE * STR];  // 16.9 KB

  const int t = threadIdx.x;
  const int block0 = blockIdx.x * TILE;

  // ---- Phase 1: gather self + mean(neigh) -> LDS tile (bf16) ----
  {
    const int r   = t >> 4;     // 0..31
    const int sub = t & 15;     // 16 threads/row (R3/R6 geometry)
    const int b   = block0 + r;
    unsigned short* crow = &Clds[r * STR];
    if (b < B) {
      const float4* f4 = (const float4*)feat;   // feature row = 32 float4
      const long srow = (long)nodes[b] * 32;
      float4 s0 = f4[srow + sub];               // elems 4sub..4sub+3
      float4 s1 = f4[srow + 16 + sub];          // elems 64+4sub..

      float ax0=0.f, ay0=0.f, az0=0.f, aw0=0.f;
      float ax1=0.f, ay1=0.f, az1=0.f, aw1=0.f;
#pragma unroll
      for (int s = 0; s < S; ++s) {
        const long nrow = (long)neigh[b * S + s] * 32;
        float4 v0 = f4[nrow + sub];
        float4 v1 = f4[nrow + 16 + sub];
        ax0 += v0.x; ay0 += v0.y; az0 += v0.z; aw0 += v0.w;
        ax1 += v1.x; ay1 += v1.y; az1 += v1.z; aw1 += v1.w;
      }
      ushort4 o;
      o.x = f2bf(s0.x); o.y = f2bf(s0.y); o.z = f2bf(s0.z); o.w = f2bf(s0.w);
      *(ushort4*)&crow[4 * sub] = o;
      o.x = f2bf(s1.x); o.y = f2bf(s1.y); o.z = f2bf(s1.z); o.w = f2bf(s1.w);
      *(ushort4*)&crow[64 + 4 * sub] = o;
      o.x = f2bf(ax0 * 0.1f); o.y = f2bf(ay0 * 0.1f);
      o.z = f2bf(az0 * 0.1f); o.w = f2bf(aw0 * 0.1f);
      *(ushort4*)&crow[128 + 4 * sub] = o;
      o.x = f2bf(ax1 * 0.1f); o.y = f2bf(ay1 * 0.1f);
      o.z = f2bf(az1 * 0.1f); o.w = f2bf(aw1 * 0.1f);
      *(ushort4*)&crow[192 + 4 * sub] = o;
    } else {
      ushort4 z; z.x = z.y = z.z = z.w = 0;
      *(ushort4*)&crow[4 * sub] = z;
      *(ushort4*)&crow[64 + 4 * sub] = z;
      *(ushort4*)&crow[128 + 4 * sub] = z;
      *(ushort4*)&crow[192 + 4 * sub] = z;
    }
  }
  __syncthreads();
  __builtin_amdgcn_sched_barrier(0);   // keep Wt loads out of phase-1 lifetime

  // ---- Phase 2: 8 waves x (32 rows x 16 cols) MFMA ----
  const int lane = t & 63;
  const int wave = t >> 6;
  const int m    = lane & 15;
  const int quad = lane >> 4;
  const int cbase = wave * 16;      // 8 waves x 16 = 128 cols

  bf16x8 bfrag[8];
#pragma unroll
  for (int ks = 0; ks < 8; ++ks)
    bfrag[ks] = *(const bf16x8*)&Wt[(cbase + m) * K + ks * 32 + quad * 8];

  f32x4 acc0 = {0.f, 0.f, 0.f, 0.f};
  f32x4 acc1 = {0.f, 0.f, 0.f, 0.f};
#pragma unroll
  for (int ks = 0; ks < 8; ++ks) {
    const int koff = ks * 32 + quad * 8;
    bf16x8 a0 = *(const bf16x8*)&Clds[(m     ) * STR + koff];
    bf16x8 a1 = *(const bf16x8*)&Clds[(16 + m) * STR + koff];
    acc0 = __builtin_amdgcn_mfma_f32_16x16x32_bf16(a0, bfrag[ks], acc0, 0, 0, 0);
    acc1 = __builtin_amdgcn_mfma_f32_16x16x32_bf16(a1, bfrag[ks], acc1, 0, 0, 0);
  }

  // C/D layout: col = lane&15, row = quad*4 + reg (verified m89/m91)
#pragma unroll
  for (int reg = 0; reg < 4; ++reg) {
    const int row0 = quad * 4 + reg;
    const int gb0 = block0 + row0;
    const int gb1 = gb0 + 16;
    if (gb0 < B) out[(size_t)gb0 * H + cbase + m] = fmaxf(acc0[reg], 0.0f);
    if (gb1 < B) out[(size_t)gb1 * H + cbase + m] = fmaxf(acc1[reg], 0.0f);
  }
}

extern "C" void kernel_launch(void* const* d_in, const int* in_sizes, int n_in,
                              void* d_out, int out_size, void* d_ws, size_t ws_size,
                              hipStream_t stream) {
  const int*   nodes = (const int*)d_in[0];
  const int*   neigh = (const int*)d_in[1];
  const float* feat  = (const float*)d_in[2];
  const float* W     = (const float*)d_in[3];
  float*       out   = (float*)d_out;
  const int B = in_sizes[0];                       // 50000

  unsigned short* Wt = (unsigned short*)d_ws;      // 64 KB
  sage_prep_wt2<<<8, 256, 0, stream>>>(W, Wt);
  const int grid = (B + 31) / 32;                  // 1563
  sage_fused3<<<grid, 512, 0, stream>>>(nodes, neigh, feat, Wt, out, B);
}